// Round 7
// baseline (239.041 us; speedup 1.0000x reference)
//
#include <hip/hip_runtime.h>

// IntraClusterGAT on MI355X — Round 13: dense attn (R10, no atomics at all)
// + CSR-slot finalize (R11 shape) with slots precomputed OFF the attn path.
//   memset icnt (0.8MB) -> prep_count (Mtr/Pbf + icnt) -> scan (CSR off,
//   block-contiguous) -> build_eids (slot=atomicAdd(cur), eids[slot]=e)
//   -> attn: R12 ping-pong pipeline, zero atomics, h-row -> H[e] streaming
//   -> finalize: 128 nodes/block (1563 blocks), per-node eids gather
//      (cc~1.31, lane-pair shares the 128B row line), fp32 sum -> MFMA @ P
//      -> R12's float4 LDS-transpose epilogue.
// ws: H 33.55MB | icnt+gbase | off | cur | eids 1MB | Mtr/Pbf  = ~37MB
// (ws >= 47.2MB proven by R10's dense path executing).

#define NV 100000
#define NN 200000
#define NCLUST 2048
#define XS 72    // X/E row stride (bf16): 144B, 16B-aligned, conflict-free

typedef __attribute__((ext_vector_type(8))) short short8;
typedef __attribute__((ext_vector_type(16))) float floatx16;

__device__ __forceinline__ unsigned short f2bf(float f) {
    union { float f; unsigned u; } v; v.f = f;
    unsigned r = v.u + 0x7fffu + ((v.u >> 16) & 1u);   // RNE
    return (unsigned short)(r >> 16);
}
__device__ __forceinline__ float bf2f(unsigned short s) {
    union { unsigned u; float f; } v; v.u = (unsigned)s << 16; return v.f;
}
__device__ __forceinline__ unsigned pack2bf(float lo, float hi) {
    union { float f; unsigned u; } a, b; a.f = lo; b.f = hi;
    unsigned ra = a.u + 0x7fffu + ((a.u >> 16) & 1u);
    unsigned rb = b.u + 0x7fffu + ((b.u >> 16) & 1u);
    return (ra >> 16) | (rb & 0xffff0000u);
}
__device__ __forceinline__ int crow(int r, int lane) {   // MFMA 32x32 C row map
    return (r & 3) + 8 * (r >> 2) + 4 * (lane >> 5);
}
// Barrier that orders LDS only: waves drain their own DS ops, then s_barrier.
// Global streaming stores intentionally stay in flight.
__device__ __forceinline__ void bar_lds() {
    __builtin_amdgcn_sched_barrier(0);
    asm volatile("s_waitcnt lgkmcnt(0)" ::: "memory");
    __builtin_amdgcn_s_barrier();
    __builtin_amdgcn_sched_barrier(0);
}

// ---- prep (Mtr/Pbf) + per-entry node counting: grid 1024x256 ----
__global__ __launch_bounds__(256) void prep_count_kernel(
    const float* __restrict__ WQ, const float* __restrict__ WK,
    const float* __restrict__ WV, const float* __restrict__ Wout,
    const float* __restrict__ head_weights, const int* __restrict__ active_heads_p,
    const int* __restrict__ cvar, const int* __restrict__ ccl,
    unsigned short* __restrict__ Mtr, unsigned short* __restrict__ Pbf,
    int* __restrict__ icnt)
{
    int o = blockIdx.x * blockDim.x + threadIdx.x;     // 0..262143
    if (o < 4096) {
        int d = o >> 6, a = o & 63;                    // Mtr[d][a] = M[a][d]
        float acc = 0.f;
        for (int j = 0; j < 64; ++j) acc += WQ[j*64 + a] * WK[j*64 + d];
        Mtr[o] = f2bf(acc * 0.125f);
    } else if (o < 8192) {
        int ah = active_heads_p[0];
        float hw = 0.f;
        for (int i = 0; i < ah; ++i) hw += head_weights[i];
        hw /= (float)ah;
        int o2 = o - 4096;
        int j = o2 >> 6, b = o2 & 63;                  // Pbf[j][b]
        float acc = 0.f;
        for (int d = 0; d < 64; ++d) acc += Wout[j*64 + d] * WV[d*64 + b];
        Pbf[o2] = f2bf(acc * hw);
    }
    int c = o >> 7, r = o & 127;
    int nid = (r < 64) ? cvar[c * 64 + r] : (NV + ccl[c * 64 + (r - 64)]);
    atomicAdd(&icnt[nid], 1);
}

// ---- off[n]: block-contiguous exclusive scan of icnt; cur[n]=off[n] ----
__global__ __launch_bounds__(256) void scan_kernel(
    const int* __restrict__ icnt, int* __restrict__ off,
    int* __restrict__ cur, int* __restrict__ gbase)
{
    __shared__ int s[256];
    __shared__ int sbase;
    const int tid = threadIdx.x;
    const int n = blockIdx.x * 256 + tid;
    int c = (n < NN) ? icnt[n] : 0;
    s[tid] = c;
    __syncthreads();
    #pragma unroll
    for (int d = 1; d < 256; d <<= 1) {        // Hillis-Steele inclusive
        int v = (tid >= d) ? s[tid - d] : 0;
        __syncthreads();
        s[tid] += v;
        __syncthreads();
    }
    if (tid == 255) sbase = atomicAdd(gbase, s[255]);
    __syncthreads();
    int o = sbase + s[tid] - c;                // exclusive + block base
    if (n < NN) { off[n] = o; cur[n] = o; }
}

// ---- eids[slot] = entry, slot claimed per node (off attn's path) ----
__global__ __launch_bounds__(256) void build_eids_kernel(
    const int* __restrict__ cvar, const int* __restrict__ ccl,
    int* __restrict__ cur, int* __restrict__ eids)
{
    int e = blockIdx.x * 256 + threadIdx.x;    // 0..262143
    int c = e >> 7, r = e & 127;
    int nid = (r < 64) ? cvar[c * 64 + r] : (NV + ccl[c * 64 + (r - 64)]);
    int slot = atomicAdd(&cur[nid], 1);
    eids[slot] = e;
}

// Full per-cluster compute: GEMM1 -> GEMM2 -> softmax -> (E-half | GEMM3)x2
// -> [optional next-cluster X park] -> dense h-row store (NO atomics).
template<bool WN>
__device__ __forceinline__ void cluster_compute(
    unsigned short* X, unsigned short* E,
    const float* biascl,
    const unsigned short* __restrict__ Mtr,
    unsigned short* __restrict__ sbase,    // H + c*128*64
    int lane, int w, int m, int hk, int r, int cb,
    short8 nx0, short8 nx1, short8 nx2, short8 nx3)
{
    // ---- GEMM1: Z = X @ M  (m-tile w, K=64; M frags from global/L1) ----
    {
        floatx16 z0 = {}, z1 = {};
        #pragma unroll
        for (int ks = 0; ks < 4; ++ks) {
            short8 mb0 = *(const short8*)(Mtr + m * 64 + ks * 16 + hk);
            short8 mb1 = *(const short8*)(Mtr + (32 + m) * 64 + ks * 16 + hk);
            short8 a = *(const short8*)&X[(w * 32 + m) * XS + ks * 16 + hk];
            z0 = __builtin_amdgcn_mfma_f32_32x32x16_bf16(a, mb0, z0, 0, 0, 0);
            z1 = __builtin_amdgcn_mfma_f32_32x32x16_bf16(a, mb1, z1, 0, 0, 0);
        }
        #pragma unroll
        for (int rr = 0; rr < 16; ++rr) {   // wave-local rows 32w..32w+31
            int row = w * 32 + crow(rr, lane);
            E[row * XS + m]      = f2bf(z0[rr]);
            E[row * XS + 32 + m] = f2bf(z1[rr]);
        }
    }

    // ---- GEMM2: scores = Z @ X^T  (m-tile w, n-tiles 0..3, K=64) ----
    floatx16 sc[4] = {{}, {}, {}, {}};
    #pragma unroll
    for (int ks = 0; ks < 4; ++ks) {
        short8 a = *(const short8*)&E[(w * 32 + m) * XS + ks * 16 + hk];
        #pragma unroll
        for (int nt = 0; nt < 4; ++nt) {
            short8 b = *(const short8*)&X[(nt * 32 + m) * XS + ks * 16 + hk];
            sc[nt] = __builtin_amdgcn_mfma_f32_32x32x16_bf16(a, b, sc[nt], 0, 0, 0);
        }
    }

    // ---- bias + leaky_relu + exp + rowsum(shfl) + normalize (all fp32) ----
    const float b2 = biascl[m], b3 = biascl[32 + m];
    #pragma unroll
    for (int rr = 0; rr < 16; ++rr) {
        float a0 = sc[0][rr], a1 = sc[1][rr], a2 = sc[2][rr] + b2, a3 = sc[3][rr] + b3;
        a0 = a0 > 0.f ? a0 : 0.2f * a0;
        a1 = a1 > 0.f ? a1 : 0.2f * a1;
        a2 = a2 > 0.f ? a2 : 0.2f * a2;
        a3 = a3 > 0.f ? a3 : 0.2f * a3;
        a0 = __expf(a0); a1 = __expf(a1); a2 = __expf(a2); a3 = __expf(a3);
        float s4 = (a0 + a1) + (a2 + a3);       // row's 32-col partial per lane
        #pragma unroll
        for (int off = 1; off < 32; off <<= 1) s4 += __shfl_xor(s4, off, 64);
        float inv = __builtin_amdgcn_rcpf(s4);  // full 128-col rowsum (half-wave)
        sc[0][rr] = a0 * inv; sc[1][rr] = a1 * inv;
        sc[2][rr] = a2 * inv; sc[3][rr] = a3 * inv;
    }

    // ---- E-half 1 (cols 0..63) over Z rows (wave-local; in-order DS) ----
    #pragma unroll
    for (int rr = 0; rr < 16; ++rr) {
        int row = w * 32 + crow(rr, lane);
        E[row * XS + m]      = f2bf(sc[0][rr]);
        E[row * XS + 32 + m] = f2bf(sc[1][rr]);
    }

    // ---- GEMM3 half 1: t = 0..63 (B cols via ds_read_u16 from X) ----
    floatx16 g0 = {}, g1 = {};
    #pragma unroll
    for (int ks = 0; ks < 4; ++ks) {
        short8 a = *(const short8*)&E[(w * 32 + m) * XS + ks * 16 + hk];
        short8 b0, b1;
        #pragma unroll
        for (int j = 0; j < 8; ++j) {
            int t = ks * 16 + hk + j;
            b0[j] = (short)X[t * XS + m];
            b1[j] = (short)X[t * XS + 32 + m];
        }
        g0 = __builtin_amdgcn_mfma_f32_32x32x16_bf16(a, b0, g0, 0, 0, 0);
        g1 = __builtin_amdgcn_mfma_f32_32x32x16_bf16(a, b1, g1, 0, 0, 0);
    }

    // ---- E-half 2 (cols 64..127) ----
    #pragma unroll
    for (int rr = 0; rr < 16; ++rr) {
        int row = w * 32 + crow(rr, lane);
        E[row * XS + m]      = f2bf(sc[2][rr]);
        E[row * XS + 32 + m] = f2bf(sc[3][rr]);
    }

    // ---- GEMM3 half 2: t = 64..127 ----
    #pragma unroll
    for (int ks = 0; ks < 4; ++ks) {
        short8 a = *(const short8*)&E[(w * 32 + m) * XS + ks * 16 + hk];
        short8 b0, b1;
        #pragma unroll
        for (int j = 0; j < 8; ++j) {
            int t = 64 + ks * 16 + hk + j;
            b0[j] = (short)X[t * XS + m];
            b1[j] = (short)X[t * XS + 32 + m];
        }
        g0 = __builtin_amdgcn_mfma_f32_32x32x16_bf16(a, b0, g0, 0, 0, 0);
        g1 = __builtin_amdgcn_mfma_f32_32x32x16_bf16(a, b1, g1, 0, 0, 0);
    }

    // ---- park next cluster's X rows into E (wave-local rows; DS in-order
    //      guarantees these land after this wave's last E A-reads above) ----
    if (WN) {
        *(short8*)&E[r * XS + cb +  0] = nx0;
        *(short8*)&E[r * XS + cb +  8] = nx1;
        *(short8*)&E[r * XS + cb + 16] = nx2;
        *(short8*)&E[r * XS + cb + 24] = nx3;
    }

    // ---- pack adjacent cols (shfl_xor 1) + dense h store (R10-validated) ----
    const bool ev = !(lane & 1);
    const int colbase = ev ? m : (31 + m);
    #pragma unroll
    for (int rr = 0; rr < 16; ++rr) {
        int row = w * 32 + crow(rr, lane);
        float a0 = g0[rr], a1 = g1[rr];
        float t0 = __shfl_xor(a0, 1, 64);
        float t1 = __shfl_xor(a1, 1, 64);
        float lo = ev ? a0 : t1;
        float hi = ev ? t0 : a1;
        unsigned pk = (unsigned)f2bf(lo) | ((unsigned)f2bf(hi) << 16);
        *(unsigned*)(sbase + (size_t)row * 64 + colbase) = pk;
    }
}

__global__ __launch_bounds__(256, 4) void attn_kernel(
    const float* __restrict__ x_var, const float* __restrict__ x_clause,
    const int* __restrict__ cvar, const int* __restrict__ ccl,
    const float* __restrict__ sat, const unsigned short* __restrict__ Mtr,
    unsigned short* __restrict__ H)
{
    __shared__ unsigned short bufA[128 * XS];  // 18432
    __shared__ unsigned short bufB[128 * XS];  // 18432
    __shared__ float bias0[64], bias1[64];     // 512
    // total ~37.4KB -> 4 blocks/CU

    const int tid = threadIdx.x, lane = tid & 63, w = tid >> 6;
    const int m = lane & 31, hk = (lane >> 5) * 8;
    const int c0 = blockIdx.x * 2;             // this block owns c0, c0+1
    const int r = tid >> 1, half = tid & 1, cb = half * 32;

    // ---- sources for BOTH clusters (issued together -> one latency) ----
    const float *src0, *src1;
    float sv0 = 0.f, sv1 = 0.f;
    if (r < 64) {
        int nid0 = cvar[c0 * 64 + r];
        int nid1 = cvar[c0 * 64 + 64 + r];     // cluster c0+1
        src0 = x_var + (size_t)nid0 * 64;
        src1 = x_var + (size_t)nid1 * 64;
    } else {
        int cid0 = ccl[c0 * 64 + (r - 64)];
        int cid1 = ccl[c0 * 64 + r];           // cluster c0+1
        src0 = x_clause + (size_t)cid0 * 64;
        src1 = x_clause + (size_t)cid1 * 64;
        if (half) { sv0 = sat[cid0]; sv1 = sat[cid1]; }
    }

    // ---- issue ALL 16 row loads (both clusters) back-to-back ----
    const float4* s40 = (const float4*)src0 + half * 8;
    const float4* s41 = (const float4*)src1 + half * 8;
    float4 v0[8], v1[8];
    #pragma unroll
    for (int i = 0; i < 8; ++i) v0[i] = s40[i];
    #pragma unroll
    for (int i = 0; i < 8; ++i) v1[i] = s41[i];

    if (r >= 64 && half) { bias0[r - 64] = sv0; bias1[r - 64] = sv1; }

    // ---- c0 -> bufA (row-major bf16) ----
    {
        union { unsigned u[16]; short8 v[4]; } h0;
        #pragma unroll
        for (int i = 0; i < 8; ++i) {
            h0.u[2*i]   = pack2bf(v0[i].x, v0[i].y);
            h0.u[2*i+1] = pack2bf(v0[i].z, v0[i].w);
        }
        #pragma unroll
        for (int i = 0; i < 4; ++i) *(short8*)&bufA[r * XS + cb + i * 8] = h0.v[i];
    }
    // ---- c1 -> 16 packed VGPRs (held across c0 compute) ----
    union { unsigned u[16]; short8 v[4]; } h1;
    #pragma unroll
    for (int i = 0; i < 8; ++i) {
        h1.u[2*i]   = pack2bf(v1[i].x, v1[i].y);
        h1.u[2*i+1] = pack2bf(v1[i].z, v1[i].w);
    }

    bar_lds();   // bufA + biases visible

    unsigned short* st0 = H + (size_t)c0 * 128 * 64;
    unsigned short* st1 = st0 + 128 * 64;

    // compute c0: X=bufA, scratch=bufB; park c1 rows into bufB near the end
    cluster_compute<true>(bufA, bufB, bias0, Mtr, st0,
                          lane, w, m, hk, r, cb,
                          h1.v[0], h1.v[1], h1.v[2], h1.v[3]);

    bar_lds();   // all waves done reading bufA/bufB(c0); c1 X now in bufB.
                 // c0's streaming stores intentionally still in flight.

    // compute c1: X=bufB, scratch=bufA
    short8 zz = {};
    cluster_compute<false>(bufB, bufA, bias1, Mtr, st1,
                           lane, w, m, hk, r, cb, zz, zz, zz, zz);
}

// CSR finalize: 128 consecutive nodes/block; per-node eids gather (cc~1.31);
// fp32 sum -> MFMA @ P -> float4 LDS-transpose epilogue (R12-validated).
__global__ __launch_bounds__(256) void finalize_kernel(
    const float* __restrict__ x_var, const float* __restrict__ x_clause,
    const unsigned short* __restrict__ H, const int* __restrict__ icnt,
    const int* __restrict__ off, const int* __restrict__ eids,
    const unsigned short* __restrict__ Pbf, const float* __restrict__ bout,
    float* __restrict__ out)
{
    __shared__ float T[4][32][68];   // 34816B
    __shared__ int scnt[128], soff[128];   // 1024B -> ~35.9KB -> 4 blocks/CU
    const int tid = threadIdx.x, lane = tid & 63, w = tid >> 6;
    const int base = blockIdx.x * 128;     // wave w owns nodes base+w*32..+31
    if (tid < 128) {
        int n = base + tid;
        bool v = n < NN;
        scnt[tid] = v ? icnt[n] : 0;
        soff[tid] = v ? off[n] : 0;
    }
    __syncthreads();

    const int m = lane & 31, hk = (lane >> 5) * 8;
    short8 pb[2][4];                              // P fragments via L1
    #pragma unroll
    for (int nt = 0; nt < 2; ++nt)
        #pragma unroll
        for (int ks = 0; ks < 4; ++ks)
            pb[nt][ks] = *(const short8*)(Pbf + (nt * 32 + m) * 64 + ks * 16 + hk);
    const float bias0 = bout[m], bias1 = bout[32 + m];

    const int lr = w * 32 + m;                 // this lane's A-frag node row
    const int cc = scnt[lr];
    const int o  = soff[lr];

    float acc[4][8] = {};                      // fp32 sum over entries
    for (int j = 0; j < cc; ++j) {
        int e = eids[o + j];
        const unsigned short* row = H + (size_t)e * 64;
        #pragma unroll
        for (int ks = 0; ks < 4; ++ks) {       // 4 independent 16B loads / j
            short8 hv = *(const short8*)(row + ks * 16 + hk);
            #pragma unroll
            for (int q = 0; q < 8; ++q)
                acc[ks][q] += bf2f((unsigned short)hv[q]);
        }
    }

    floatx16 c0 = {}, c1 = {};
    #pragma unroll
    for (int ks = 0; ks < 4; ++ks) {
        short8 a;
        #pragma unroll
        for (int q = 0; q < 8; ++q) a[q] = (short)f2bf(acc[ks][q]);
        c0 = __builtin_amdgcn_mfma_f32_32x32x16_bf16(a, pb[0][ks], c0, 0, 0, 0);
        c1 = __builtin_amdgcn_mfma_f32_32x32x16_bf16(a, pb[1][ks], c1, 0, 0, 0);
    }

    // ---- phase A: stage (c*inv + bias) to wave-private T ----
    #pragma unroll
    for (int rr = 0; rr < 16; ++rr) {
        int lr32 = crow(rr, lane);             // 0..31 within tile
        float inv = 1.0f / fmaxf((float)scnt[w * 32 + lr32], 1.0f);
        T[w][lr32][m]      = c0[rr] * inv + bias0;
        T[w][lr32][32 + m] = c1[rr] * inv + bias1;
    }
    // wave-local DS is in-order: reads below see this wave's writes.
    // ---- phase B: float4 x-add + out-store (2 rows per lane-pair) ----
    const int r2 = lane >> 1, cb2 = (lane & 1) * 32;
    int n2 = base + w * 32 + r2;
    if (n2 < NN) {
        const float* xr = (n2 < NV) ? (x_var + (size_t)n2 * 64)
                                    : (x_clause + (size_t)(n2 - NV) * 64);
        float* orow = out + (size_t)n2 * 64;
        #pragma unroll
        for (int j = 0; j < 8; ++j) {
            float4 t = *(const float4*)&T[w][r2][cb2 + 4 * j];
            float4 xv = *(const float4*)&xr[cb2 + 4 * j];
            float4 ov;
            ov.x = t.x + xv.x; ov.y = t.y + xv.y;
            ov.z = t.z + xv.z; ov.w = t.w + xv.w;
            *(float4*)&orow[cb2 + 4 * j] = ov;
        }
    }
}

extern "C" void kernel_launch(void* const* d_in, const int* in_sizes, int n_in,
                              void* d_out, int out_size, void* d_ws, size_t ws_size,
                              hipStream_t stream)
{
    const float* x_var        = (const float*)d_in[0];
    const float* x_clause     = (const float*)d_in[1];
    const int*   cvar         = (const int*)d_in[4];
    const int*   ccl          = (const int*)d_in[5];
    const float* sat          = (const float*)d_in[6];
    const int*   active_heads = (const int*)d_in[7];
    const float* WQ           = (const float*)d_in[8];
    const float* WK           = (const float*)d_in[9];
    const float* WV           = (const float*)d_in[10];
    const float* head_weights = (const float*)d_in[11];
    const float* Wout         = (const float*)d_in[12];
    const float* bout         = (const float*)d_in[13];

    // ---- workspace layout (~37MB; ws >= 47.2MB proven in R10) ----
    const size_t H_BYTES   = (size_t)NCLUST * 128 * 64 * 2;    // 33,554,432
    const size_t ICNT_OFF  = H_BYTES;
    const size_t GBASE_OFF = ICNT_OFF + (size_t)NN * 4;        // right after icnt
    const size_t OFF_OFF   = ICNT_OFF + 800256;
    const size_t CUR_OFF   = OFF_OFF + 800256;
    const size_t EIDS_OFF  = CUR_OFF + 800256;
    const size_t MTR_OFF   = EIDS_OFF + (size_t)NCLUST * 128 * 4 + 256;

    unsigned short* H   = (unsigned short*)d_ws;
    int* icnt  = (int*)((char*)d_ws + ICNT_OFF);
    int* gbase = (int*)((char*)d_ws + GBASE_OFF);
    int* off   = (int*)((char*)d_ws + OFF_OFF);
    int* cur   = (int*)((char*)d_ws + CUR_OFF);
    int* eids  = (int*)((char*)d_ws + EIDS_OFF);
    unsigned short* Mtr = (unsigned short*)((char*)d_ws + MTR_OFF);
    unsigned short* Pbf = Mtr + 4096;

    hipMemsetAsync(icnt, 0, (size_t)NN * 4 + 256, stream);     // icnt + gbase
    prep_count_kernel<<<1024, 256, 0, stream>>>(
        WQ, WK, WV, Wout, head_weights, active_heads, cvar, ccl, Mtr, Pbf, icnt);
    scan_kernel<<<(NN + 255) / 256, 256, 0, stream>>>(icnt, off, cur, gbase);
    build_eids_kernel<<<1024, 256, 0, stream>>>(cvar, ccl, cur, eids);
    attn_kernel<<<NCLUST / 2, 256, 0, stream>>>(
        x_var, x_clause, cvar, ccl, sat, Mtr, H);
    finalize_kernel<<<(NN + 127) / 128, 256, 0, stream>>>(
        x_var, x_clause, H, icnt, off, eids, Pbf, bout, (float*)d_out);
}

// Round 8
// 222.744 us; speedup vs baseline: 1.0732x; 1.0732x over previous
//
#include <hip/hip_runtime.h>

// IntraClusterGAT on MI355X — Round 14: associativity — project inside attn.
//   agg(attn@X)@P^T == agg(attn@(X@P^T)).  After GEMM2, raw X is dead; an
//   in-place XP = X@P^T (8 MFMA/wave, A staged to regs, 2 extra barriers)
//   makes GEMM3 emit projected h. Scatter unchanged (R12's proven path).
//   finalize becomes pure streaming elementwise: out = x + acc*inv + b
//   (129MB grid-stride, ~25µs) replacing the ~40µs gather+MFMA version.
//   prep: R12's merged weight-prep + 26.4MB zeroing. 3 dispatches total.
// ws: acc[NN*64] bf16 | countv[NN] f32 | Mtr 4096 bf16 | Pbf 4096 bf16

#define NV 100000
#define NN 200000
#define NCLUST 2048
#define XS 72    // X/E row stride (bf16): 144B, 16B-aligned, conflict-free

typedef __attribute__((ext_vector_type(8))) short short8;
typedef __attribute__((ext_vector_type(16))) float floatx16;
typedef __attribute__((ext_vector_type(4))) unsigned uint4v;

__device__ __forceinline__ unsigned short f2bf(float f) {
    union { float f; unsigned u; } v; v.f = f;
    unsigned r = v.u + 0x7fffu + ((v.u >> 16) & 1u);   // RNE
    return (unsigned short)(r >> 16);
}
__device__ __forceinline__ float bf2f(unsigned short s) {
    union { unsigned u; float f; } v; v.u = (unsigned)s << 16; return v.f;
}
__device__ __forceinline__ unsigned pack2bf(float lo, float hi) {
    union { float f; unsigned u; } a, b; a.f = lo; b.f = hi;
    unsigned ra = a.u + 0x7fffu + ((a.u >> 16) & 1u);
    unsigned rb = b.u + 0x7fffu + ((b.u >> 16) & 1u);
    return (ra >> 16) | (rb & 0xffff0000u);
}
__device__ __forceinline__ int crow(int r, int lane) {   // MFMA 32x32 C row map
    return (r & 3) + 8 * (r >> 2) + 4 * (lane >> 5);
}
// Barrier that orders LDS only: waves drain their own DS ops, then s_barrier.
// Global atomics (accum scatter, countv) intentionally stay in flight.
__device__ __forceinline__ void bar_lds() {
    __builtin_amdgcn_sched_barrier(0);
    asm volatile("s_waitcnt lgkmcnt(0)" ::: "memory");
    __builtin_amdgcn_s_barrier();
    __builtin_amdgcn_sched_barrier(0);
}

// ---- prep: Mtr/Pbf weights + zero acc/countv (replaces memset) ----
#define ZU4 1650000   // (NN*64*2 + NN*4) / 16 bytes -> uint4 count
__global__ __launch_bounds__(256) void prep_kernel(
    const float* __restrict__ WQ, const float* __restrict__ WK,
    const float* __restrict__ WV, const float* __restrict__ Wout,
    const float* __restrict__ head_weights, const int* __restrict__ active_heads_p,
    unsigned short* __restrict__ Mtr, unsigned short* __restrict__ Pbf,
    uint4v* __restrict__ zbase)
{
    int o = blockIdx.x * blockDim.x + threadIdx.x;
    if (o < 4096) {
        int d = o >> 6, a = o & 63;                       // Mtr[d][a] = M[a][d]
        float acc = 0.f;
        for (int j = 0; j < 64; ++j) acc += WQ[j*64 + a] * WK[j*64 + d];
        Mtr[o] = f2bf(acc * 0.125f);
    } else if (o < 8192) {
        int ah = active_heads_p[0];
        float hw = 0.f;
        for (int i = 0; i < ah; ++i) hw += head_weights[i];
        hw /= (float)ah;
        int o2 = o - 4096;
        int j = o2 >> 6, b = o2 & 63;                     // Pbf[j][b]
        float acc = 0.f;
        for (int d = 0; d < 64; ++d) acc += Wout[j*64 + d] * WV[d*64 + b];
        Pbf[o2] = f2bf(acc * hw);
    }
    // grid-stride zero of acc + countv (contiguous, 16B-multiple)
    uint4v z = {0u, 0u, 0u, 0u};
    for (int j = o; j < ZU4; j += 262144) zbase[j] = z;
}

// Full per-cluster compute: GEMM1 -> GEMM2 -> [bar, XP=X@P^T in-place,
// softmax, bar] -> (E-half | GEMM3)x2 (now emits PROJECTED h) ->
// [optional next-cluster X park] -> atomic scatter.
template<bool WN>
__device__ __forceinline__ void cluster_compute(
    unsigned short* X, unsigned short* E,
    const int* ids, const float* biascl,
    const unsigned short* __restrict__ Mtr,
    const unsigned short* __restrict__ Pbf,
    unsigned short* __restrict__ accum_bf,
    int lane, int w, int m, int hk, int r, int cb,
    short8 nx0, short8 nx1, short8 nx2, short8 nx3)
{
    // ---- GEMM1: Z = X @ M  (m-tile w, K=64; M frags from global/L1) ----
    {
        floatx16 z0 = {}, z1 = {};
        #pragma unroll
        for (int ks = 0; ks < 4; ++ks) {
            short8 mb0 = *(const short8*)(Mtr + m * 64 + ks * 16 + hk);
            short8 mb1 = *(const short8*)(Mtr + (32 + m) * 64 + ks * 16 + hk);
            short8 a = *(const short8*)&X[(w * 32 + m) * XS + ks * 16 + hk];
            z0 = __builtin_amdgcn_mfma_f32_32x32x16_bf16(a, mb0, z0, 0, 0, 0);
            z1 = __builtin_amdgcn_mfma_f32_32x32x16_bf16(a, mb1, z1, 0, 0, 0);
        }
        #pragma unroll
        for (int rr = 0; rr < 16; ++rr) {   // wave-local rows 32w..32w+31
            int row = w * 32 + crow(rr, lane);
            E[row * XS + m]      = f2bf(z0[rr]);
            E[row * XS + 32 + m] = f2bf(z1[rr]);
        }
    }

    // ---- GEMM2: scores = Z @ X^T  (m-tile w, n-tiles 0..3, K=64) ----
    floatx16 sc[4] = {{}, {}, {}, {}};
    #pragma unroll
    for (int ks = 0; ks < 4; ++ks) {
        short8 a = *(const short8*)&E[(w * 32 + m) * XS + ks * 16 + hk];
        #pragma unroll
        for (int nt = 0; nt < 4; ++nt) {
            short8 b = *(const short8*)&X[(nt * 32 + m) * XS + ks * 16 + hk];
            sc[nt] = __builtin_amdgcn_mfma_f32_32x32x16_bf16(a, b, sc[nt], 0, 0, 0);
        }
    }

    // ---- barrier: every wave is done reading raw X (GEMM1 A, GEMM2 B) ----
    bar_lds();

    // ---- XP = X @ P^T, in-place into X rows. A-frags staged to registers
    //      first so this wave's writes cannot race its own reads; cross-wave
    //      visibility handled by the barrier after softmax. ----
    {
        short8 xa[4];
        #pragma unroll
        for (int ks = 0; ks < 4; ++ks)
            xa[ks] = *(const short8*)&X[(w * 32 + m) * XS + ks * 16 + hk];
        floatx16 xp0 = {}, xp1 = {};
        #pragma unroll
        for (int ks = 0; ks < 4; ++ks) {
            short8 p0 = *(const short8*)(Pbf + m * 64 + ks * 16 + hk);
            short8 p1 = *(const short8*)(Pbf + (32 + m) * 64 + ks * 16 + hk);
            xp0 = __builtin_amdgcn_mfma_f32_32x32x16_bf16(xa[ks], p0, xp0, 0, 0, 0);
            xp1 = __builtin_amdgcn_mfma_f32_32x32x16_bf16(xa[ks], p1, xp1, 0, 0, 0);
        }
        #pragma unroll
        for (int rr = 0; rr < 16; ++rr) {
            int row = w * 32 + crow(rr, lane);
            X[row * XS + m]      = f2bf(xp0[rr]);
            X[row * XS + 32 + m] = f2bf(xp1[rr]);
        }
    }

    // ---- bias + leaky_relu + exp + rowsum(shfl) + normalize (all fp32);
    //      VALU work overlaps the XP ds_write drain ----
    const float b2 = biascl[m], b3 = biascl[32 + m];
    #pragma unroll
    for (int rr = 0; rr < 16; ++rr) {
        float a0 = sc[0][rr], a1 = sc[1][rr], a2 = sc[2][rr] + b2, a3 = sc[3][rr] + b3;
        a0 = a0 > 0.f ? a0 : 0.2f * a0;
        a1 = a1 > 0.f ? a1 : 0.2f * a1;
        a2 = a2 > 0.f ? a2 : 0.2f * a2;
        a3 = a3 > 0.f ? a3 : 0.2f * a3;
        a0 = __expf(a0); a1 = __expf(a1); a2 = __expf(a2); a3 = __expf(a3);
        float s4 = (a0 + a1) + (a2 + a3);       // row's 32-col partial per lane
        #pragma unroll
        for (int off = 1; off < 32; off <<= 1) s4 += __shfl_xor(s4, off, 64);
        float inv = __builtin_amdgcn_rcpf(s4);  // full 128-col rowsum (half-wave)
        sc[0][rr] = a0 * inv; sc[1][rr] = a1 * inv;
        sc[2][rr] = a2 * inv; sc[3][rr] = a3 * inv;
    }

    // ---- barrier: all waves' XP rows visible before GEMM3 B-reads ----
    bar_lds();

    // ---- E-half 1 (cols 0..63) over Z rows (wave-local; in-order DS) ----
    #pragma unroll
    for (int rr = 0; rr < 16; ++rr) {
        int row = w * 32 + crow(rr, lane);
        E[row * XS + m]      = f2bf(sc[0][rr]);
        E[row * XS + 32 + m] = f2bf(sc[1][rr]);
    }

    // ---- GEMM3 half 1: t = 0..63 (B cols from XP -> projected h) ----
    floatx16 g0 = {}, g1 = {};
    #pragma unroll
    for (int ks = 0; ks < 4; ++ks) {
        short8 a = *(const short8*)&E[(w * 32 + m) * XS + ks * 16 + hk];
        short8 b0, b1;
        #pragma unroll
        for (int j = 0; j < 8; ++j) {
            int t = ks * 16 + hk + j;
            b0[j] = (short)X[t * XS + m];
            b1[j] = (short)X[t * XS + 32 + m];
        }
        g0 = __builtin_amdgcn_mfma_f32_32x32x16_bf16(a, b0, g0, 0, 0, 0);
        g1 = __builtin_amdgcn_mfma_f32_32x32x16_bf16(a, b1, g1, 0, 0, 0);
    }

    // ---- E-half 2 (cols 64..127) ----
    #pragma unroll
    for (int rr = 0; rr < 16; ++rr) {
        int row = w * 32 + crow(rr, lane);
        E[row * XS + m]      = f2bf(sc[2][rr]);
        E[row * XS + 32 + m] = f2bf(sc[3][rr]);
    }

    // ---- GEMM3 half 2: t = 64..127 ----
    #pragma unroll
    for (int ks = 0; ks < 4; ++ks) {
        short8 a = *(const short8*)&E[(w * 32 + m) * XS + ks * 16 + hk];
        short8 b0, b1;
        #pragma unroll
        for (int j = 0; j < 8; ++j) {
            int t = 64 + ks * 16 + hk + j;
            b0[j] = (short)X[t * XS + m];
            b1[j] = (short)X[t * XS + 32 + m];
        }
        g0 = __builtin_amdgcn_mfma_f32_32x32x16_bf16(a, b0, g0, 0, 0, 0);
        g1 = __builtin_amdgcn_mfma_f32_32x32x16_bf16(a, b1, g1, 0, 0, 0);
    }

    // ---- park next cluster's X rows into E (wave-local rows; DS in-order
    //      guarantees these land after this wave's last E A-reads above) ----
    if (WN) {
        *(short8*)&E[r * XS + cb +  0] = nx0;
        *(short8*)&E[r * XS + cb +  8] = nx1;
        *(short8*)&E[r * XS + cb + 16] = nx2;
        *(short8*)&E[r * XS + cb + 24] = nx3;
    }

    // ---- pack adjacent cols (shfl_xor 1) + pk_add_bf16 scatter (projected) ----
    const bool ev = !(lane & 1);
    const int colbase = ev ? m : (31 + m);
    #pragma unroll
    for (int rr = 0; rr < 16; ++rr) {
        int row = w * 32 + crow(rr, lane);
        int nid = ids[row];
        float a0 = g0[rr], a1 = g1[rr];
        float t0 = __shfl_xor(a0, 1, 64);
        float t1 = __shfl_xor(a1, 1, 64);
        float lo = ev ? a0 : t1;
        float hi = ev ? t0 : a1;
        unsigned pk = (unsigned)f2bf(lo) | ((unsigned)f2bf(hi) << 16);
        unsigned long long addr =
            (unsigned long long)(accum_bf + (size_t)nid * 64 + colbase);
        asm volatile("global_atomic_pk_add_bf16 %0, %1, off"
                     :: "v"(addr), "v"(pk) : "memory");
    }
}

__global__ __launch_bounds__(256, 4) void attn_kernel(
    const float* __restrict__ x_var, const float* __restrict__ x_clause,
    const int* __restrict__ cvar, const int* __restrict__ ccl,
    const float* __restrict__ sat, const unsigned short* __restrict__ Mtr,
    const unsigned short* __restrict__ Pbf,
    unsigned short* __restrict__ accum_bf, float* __restrict__ countv)
{
    __shared__ unsigned short bufA[128 * XS];  // 18432
    __shared__ unsigned short bufB[128 * XS];  // 18432
    __shared__ int   ids0[128], ids1[128];     // 1024
    __shared__ float bias0[64], bias1[64];     // 512
    // total 38400 B -> 4 blocks/CU

    const int tid = threadIdx.x, lane = tid & 63, w = tid >> 6;
    const int m = lane & 31, hk = (lane >> 5) * 8;
    const int c0 = blockIdx.x * 2;             // this block owns c0, c0+1
    const int r = tid >> 1, half = tid & 1, cb = half * 32;

    // ---- ids for BOTH clusters (issued together -> one latency) ----
    int nid0, nid1;
    const float *src0, *src1;
    float sv0 = 0.f, sv1 = 0.f;
    if (r < 64) {
        nid0 = cvar[c0 * 64 + r];
        nid1 = cvar[c0 * 64 + 64 + r];         // cluster c0+1
        src0 = x_var + (size_t)nid0 * 64;
        src1 = x_var + (size_t)nid1 * 64;
    } else {
        int cid0 = ccl[c0 * 64 + (r - 64)];
        int cid1 = ccl[c0 * 64 + r];           // cluster c0+1
        nid0 = NV + cid0; nid1 = NV + cid1;
        src0 = x_clause + (size_t)cid0 * 64;
        src1 = x_clause + (size_t)cid1 * 64;
        if (half) { sv0 = sat[cid0]; sv1 = sat[cid1]; }
    }

    // ---- issue ALL 16 row loads (both clusters) back-to-back ----
    const float4* s40 = (const float4*)src0 + half * 8;
    const float4* s41 = (const float4*)src1 + half * 8;
    float4 v0[8], v1[8];
    #pragma unroll
    for (int i = 0; i < 8; ++i) v0[i] = s40[i];
    #pragma unroll
    for (int i = 0; i < 8; ++i) v1[i] = s41[i];

    if (!half) {
        ids0[r] = nid0; ids1[r] = nid1;
        atomicAdd(&countv[nid0], 1.0f);
        atomicAdd(&countv[nid1], 1.0f);
    }
    if (r >= 64 && half) { bias0[r - 64] = sv0; bias1[r - 64] = sv1; }

    // ---- c0 -> bufA (row-major bf16) ----
    {
        union { unsigned u[16]; short8 v[4]; } h0;
        #pragma unroll
        for (int i = 0; i < 8; ++i) {
            h0.u[2*i]   = pack2bf(v0[i].x, v0[i].y);
            h0.u[2*i+1] = pack2bf(v0[i].z, v0[i].w);
        }
        #pragma unroll
        for (int i = 0; i < 4; ++i) *(short8*)&bufA[r * XS + cb + i * 8] = h0.v[i];
    }
    // ---- c1 -> 16 packed VGPRs (held across c0 compute) ----
    union { unsigned u[16]; short8 v[4]; } h1;
    #pragma unroll
    for (int i = 0; i < 8; ++i) {
        h1.u[2*i]   = pack2bf(v1[i].x, v1[i].y);
        h1.u[2*i+1] = pack2bf(v1[i].z, v1[i].w);
    }

    bar_lds();   // bufA visible; countv/ids atomics may still fly

    // compute c0: X=bufA, scratch=bufB; park c1 rows into bufB near the end
    cluster_compute<true>(bufA, bufB, ids0, bias0, Mtr, Pbf, accum_bf,
                          lane, w, m, hk, r, cb,
                          h1.v[0], h1.v[1], h1.v[2], h1.v[3]);

    bar_lds();   // all waves done reading bufA/bufB(c0); c1 X now in bufB.
                 // c0's atomic scatter intentionally still in flight.

    // compute c1: X=bufB, scratch=bufA
    short8 zz = {};
    cluster_compute<false>(bufB, bufA, ids1, bias1, Mtr, Pbf, accum_bf,
                           lane, w, m, hk, r, cb, zz, zz, zz, zz);
}

// finalize v4: acc already projected -> pure streaming elementwise.
//   out[n][:] = x[n][:] + acc[n][:] * inv(cnt[n]) + b[:]
// Grid-stride, 2048 blocks; each thread owns a fixed 8-col octet (stride
// 2048*256 is a multiple of 8 -> o8 constant -> bias in registers).
__global__ __launch_bounds__(256) void finalize_kernel(
    const float* __restrict__ x_var, const float* __restrict__ x_clause,
    const unsigned short* __restrict__ acc, const float* __restrict__ countv,
    const float* __restrict__ bout, float* __restrict__ out)
{
    const int t0 = blockIdx.x * 256 + threadIdx.x;
    const int o8 = t0 & 7;
    const int co = o8 * 8;
    const float4 b0 = *(const float4*)&bout[co];
    const float4 b1 = *(const float4*)&bout[co + 4];
    for (int i = t0; i < NN * 8; i += 2048 * 256) {
        int n = i >> 3;
        float inv = 1.0f / fmaxf(countv[n], 1.0f);
        const float* xr = (n < NV) ? (x_var + (size_t)n * 64)
                                   : (x_clause + (size_t)(n - NV) * 64);
        short8 a = *(const short8*)(acc + (size_t)n * 64 + co);
        float4 x0 = *(const float4*)(xr + co);
        float4 x1 = *(const float4*)(xr + co + 4);
        float4 o0, o1;
        o0.x = x0.x + bf2f((unsigned short)a[0]) * inv + b0.x;
        o0.y = x0.y + bf2f((unsigned short)a[1]) * inv + b0.y;
        o0.z = x0.z + bf2f((unsigned short)a[2]) * inv + b0.z;
        o0.w = x0.w + bf2f((unsigned short)a[3]) * inv + b0.w;
        o1.x = x1.x + bf2f((unsigned short)a[4]) * inv + b1.x;
        o1.y = x1.y + bf2f((unsigned short)a[5]) * inv + b1.y;
        o1.z = x1.z + bf2f((unsigned short)a[6]) * inv + b1.z;
        o1.w = x1.w + bf2f((unsigned short)a[7]) * inv + b1.w;
        *(float4*)(out + (size_t)n * 64 + co)     = o0;
        *(float4*)(out + (size_t)n * 64 + co + 4) = o1;
    }
}

extern "C" void kernel_launch(void* const* d_in, const int* in_sizes, int n_in,
                              void* d_out, int out_size, void* d_ws, size_t ws_size,
                              hipStream_t stream)
{
    const float* x_var        = (const float*)d_in[0];
    const float* x_clause     = (const float*)d_in[1];
    const int*   cvar         = (const int*)d_in[4];
    const int*   ccl          = (const int*)d_in[5];
    const float* sat          = (const float*)d_in[6];
    const int*   active_heads = (const int*)d_in[7];
    const float* WQ           = (const float*)d_in[8];
    const float* WK           = (const float*)d_in[9];
    const float* WV           = (const float*)d_in[10];
    const float* head_weights = (const float*)d_in[11];
    const float* Wout         = (const float*)d_in[12];
    const float* bout         = (const float*)d_in[13];

    unsigned short* accum_bf = (unsigned short*)d_ws;          // NN*64 bf16
    float* countv = (float*)(accum_bf + (size_t)NN * 64);      // NN f32
    unsigned short* Mtr = (unsigned short*)(countv + NN);      // 4096 bf16
    unsigned short* Pbf = Mtr + 4096;                          // 4096 bf16

    // prep zeroes acc+countv itself (26.4MB contiguous) -> no memset
    prep_kernel<<<1024, 256, 0, stream>>>(WQ, WK, WV, Wout, head_weights,
                                          active_heads, Mtr, Pbf,
                                          (uint4v*)d_ws);
    attn_kernel<<<NCLUST / 2, 256, 0, stream>>>(
        x_var, x_clause, cvar, ccl, sat, Mtr, Pbf, accum_bf, countv);
    finalize_kernel<<<2048, 256, 0, stream>>>(
        x_var, x_clause, accum_bf, countv, bout, (float*)d_out);
}

// Round 9
// 216.352 us; speedup vs baseline: 1.1049x; 1.0295x over previous
//
#include <hip/hip_runtime.h>

// IntraClusterGAT on MI355X — Round 15: exact R12 revert (best, 209.7) +
// countv atomics moved out of attn (6% of attn's atomic count, which R6-R14
// evidence pins as the attn wall: 8.4M pk-atomics / 58µs ≈ TCC atomic rate).
//   memset countv (0.8MB) -> prep: Mtr/Pbf + zero accum (25.6MB) + count
//   entries into countv (one thread per entry, 262K f32 atomicAdds)
//   -> attn: R12 ping-pong 2-cluster pipeline, scatter-only atomics
//   -> finalize: R12's MFMA + float4 LDS-transpose epilogue (782 blocks).
// ws: accum_bf[NN*64] bf16 | countv[NN] f32 | Mtr 4096 bf16 | Pbf 4096 bf16

#define NV 100000
#define NN 200000
#define NCLUST 2048
#define XS 72    // X/E row stride (bf16): 144B, 16B-aligned, conflict-free

typedef __attribute__((ext_vector_type(8))) short short8;
typedef __attribute__((ext_vector_type(16))) float floatx16;
typedef __attribute__((ext_vector_type(4))) unsigned uint4v;

__device__ __forceinline__ unsigned short f2bf(float f) {
    union { float f; unsigned u; } v; v.f = f;
    unsigned r = v.u + 0x7fffu + ((v.u >> 16) & 1u);   // RNE
    return (unsigned short)(r >> 16);
}
__device__ __forceinline__ unsigned pack2bf(float lo, float hi) {
    union { float f; unsigned u; } a, b; a.f = lo; b.f = hi;
    unsigned ra = a.u + 0x7fffu + ((a.u >> 16) & 1u);
    unsigned rb = b.u + 0x7fffu + ((b.u >> 16) & 1u);
    return (ra >> 16) | (rb & 0xffff0000u);
}
__device__ __forceinline__ int crow(int r, int lane) {   // MFMA 32x32 C row map
    return (r & 3) + 8 * (r >> 2) + 4 * (lane >> 5);
}
// Barrier that orders LDS only: waves drain their own DS ops, then s_barrier.
// Global atomics (accum scatter) intentionally stay in flight.
__device__ __forceinline__ void bar_lds() {
    __builtin_amdgcn_sched_barrier(0);
    asm volatile("s_waitcnt lgkmcnt(0)" ::: "memory");
    __builtin_amdgcn_s_barrier();
    __builtin_amdgcn_sched_barrier(0);
}

// ---- prep: Mtr/Pbf weights + zero accum_bf + count entries -> countv ----
#define ZU4 1600000   // NN*64*2 / 16 bytes -> uint4 count (accum only)
__global__ __launch_bounds__(256) void prep_kernel(
    const float* __restrict__ WQ, const float* __restrict__ WK,
    const float* __restrict__ WV, const float* __restrict__ Wout,
    const float* __restrict__ head_weights, const int* __restrict__ active_heads_p,
    const int* __restrict__ cvar, const int* __restrict__ ccl,
    unsigned short* __restrict__ Mtr, unsigned short* __restrict__ Pbf,
    uint4v* __restrict__ zbase, float* __restrict__ countv)
{
    int o = blockIdx.x * blockDim.x + threadIdx.x;     // 0..262143
    if (o < 4096) {
        int d = o >> 6, a = o & 63;                       // Mtr[d][a] = M[a][d]
        float acc = 0.f;
        for (int j = 0; j < 64; ++j) acc += WQ[j*64 + a] * WK[j*64 + d];
        Mtr[o] = f2bf(acc * 0.125f);
    } else if (o < 8192) {
        int ah = active_heads_p[0];
        float hw = 0.f;
        for (int i = 0; i < ah; ++i) hw += head_weights[i];
        hw /= (float)ah;
        int o2 = o - 4096;
        int j = o2 >> 6, b = o2 & 63;                     // Pbf[j][b]
        float acc = 0.f;
        for (int d = 0; d < 64; ++d) acc += Wout[j*64 + d] * WV[d*64 + b];
        Pbf[o2] = f2bf(acc * hw);
    }
    // per-entry node counting (countv pre-zeroed by the 0.8MB memset)
    {
        int c = o >> 7, r = o & 127;
        int nid = (r < 64) ? cvar[c * 64 + r] : (NV + ccl[c * 64 + (r - 64)]);
        atomicAdd(&countv[nid], 1.0f);
    }
    // grid-stride zero of accum_bf (25.6MB contiguous)
    uint4v z = {0u, 0u, 0u, 0u};
    for (int j = o; j < ZU4; j += 262144) zbase[j] = z;
}

// Full per-cluster compute (R12-exact): GEMM1 -> GEMM2 -> softmax ->
// (E-half | GEMM3)x2 -> [optional next-cluster X park] -> atomic scatter.
template<bool WN>
__device__ __forceinline__ void cluster_compute(
    unsigned short* X, unsigned short* E,
    const int* ids, const float* biascl,
    const unsigned short* __restrict__ Mtr,
    unsigned short* __restrict__ accum_bf,
    int lane, int w, int m, int hk, int r, int cb,
    short8 nx0, short8 nx1, short8 nx2, short8 nx3)
{
    // ---- GEMM1: Z = X @ M  (m-tile w, K=64; M frags from global/L1) ----
    {
        floatx16 z0 = {}, z1 = {};
        #pragma unroll
        for (int ks = 0; ks < 4; ++ks) {
            short8 mb0 = *(const short8*)(Mtr + m * 64 + ks * 16 + hk);
            short8 mb1 = *(const short8*)(Mtr + (32 + m) * 64 + ks * 16 + hk);
            short8 a = *(const short8*)&X[(w * 32 + m) * XS + ks * 16 + hk];
            z0 = __builtin_amdgcn_mfma_f32_32x32x16_bf16(a, mb0, z0, 0, 0, 0);
            z1 = __builtin_amdgcn_mfma_f32_32x32x16_bf16(a, mb1, z1, 0, 0, 0);
        }
        #pragma unroll
        for (int rr = 0; rr < 16; ++rr) {   // wave-local rows 32w..32w+31
            int row = w * 32 + crow(rr, lane);
            E[row * XS + m]      = f2bf(z0[rr]);
            E[row * XS + 32 + m] = f2bf(z1[rr]);
        }
    }

    // ---- GEMM2: scores = Z @ X^T  (m-tile w, n-tiles 0..3, K=64) ----
    floatx16 sc[4] = {{}, {}, {}, {}};
    #pragma unroll
    for (int ks = 0; ks < 4; ++ks) {
        short8 a = *(const short8*)&E[(w * 32 + m) * XS + ks * 16 + hk];
        #pragma unroll
        for (int nt = 0; nt < 4; ++nt) {
            short8 b = *(const short8*)&X[(nt * 32 + m) * XS + ks * 16 + hk];
            sc[nt] = __builtin_amdgcn_mfma_f32_32x32x16_bf16(a, b, sc[nt], 0, 0, 0);
        }
    }

    // ---- bias + leaky_relu + exp + rowsum(shfl) + normalize (all fp32) ----
    const float b2 = biascl[m], b3 = biascl[32 + m];
    #pragma unroll
    for (int rr = 0; rr < 16; ++rr) {
        float a0 = sc[0][rr], a1 = sc[1][rr], a2 = sc[2][rr] + b2, a3 = sc[3][rr] + b3;
        a0 = a0 > 0.f ? a0 : 0.2f * a0;
        a1 = a1 > 0.f ? a1 : 0.2f * a1;
        a2 = a2 > 0.f ? a2 : 0.2f * a2;
        a3 = a3 > 0.f ? a3 : 0.2f * a3;
        a0 = __expf(a0); a1 = __expf(a1); a2 = __expf(a2); a3 = __expf(a3);
        float s4 = (a0 + a1) + (a2 + a3);       // row's 32-col partial per lane
        #pragma unroll
        for (int off = 1; off < 32; off <<= 1) s4 += __shfl_xor(s4, off, 64);
        float inv = __builtin_amdgcn_rcpf(s4);  // full 128-col rowsum (half-wave)
        sc[0][rr] = a0 * inv; sc[1][rr] = a1 * inv;
        sc[2][rr] = a2 * inv; sc[3][rr] = a3 * inv;
    }

    // ---- E-half 1 (cols 0..63) over Z rows (wave-local; in-order DS) ----
    #pragma unroll
    for (int rr = 0; rr < 16; ++rr) {
        int row = w * 32 + crow(rr, lane);
        E[row * XS + m]      = f2bf(sc[0][rr]);
        E[row * XS + 32 + m] = f2bf(sc[1][rr]);
    }

    // ---- GEMM3 half 1: t = 0..63 (B cols via ds_read_u16 from X) ----
    floatx16 g0 = {}, g1 = {};
    #pragma unroll
    for (int ks = 0; ks < 4; ++ks) {
        short8 a = *(const short8*)&E[(w * 32 + m) * XS + ks * 16 + hk];
        short8 b0, b1;
        #pragma unroll
        for (int j = 0; j < 8; ++j) {
            int t = ks * 16 + hk + j;
            b0[j] = (short)X[t * XS + m];
            b1[j] = (short)X[t * XS + 32 + m];
        }
        g0 = __builtin_amdgcn_mfma_f32_32x32x16_bf16(a, b0, g0, 0, 0, 0);
        g1 = __builtin_amdgcn_mfma_f32_32x32x16_bf16(a, b1, g1, 0, 0, 0);
    }

    // ---- E-half 2 (cols 64..127) ----
    #pragma unroll
    for (int rr = 0; rr < 16; ++rr) {
        int row = w * 32 + crow(rr, lane);
        E[row * XS + m]      = f2bf(sc[2][rr]);
        E[row * XS + 32 + m] = f2bf(sc[3][rr]);
    }

    // ---- GEMM3 half 2: t = 64..127 ----
    #pragma unroll
    for (int ks = 0; ks < 4; ++ks) {
        short8 a = *(const short8*)&E[(w * 32 + m) * XS + ks * 16 + hk];
        short8 b0, b1;
        #pragma unroll
        for (int j = 0; j < 8; ++j) {
            int t = 64 + ks * 16 + hk + j;
            b0[j] = (short)X[t * XS + m];
            b1[j] = (short)X[t * XS + 32 + m];
        }
        g0 = __builtin_amdgcn_mfma_f32_32x32x16_bf16(a, b0, g0, 0, 0, 0);
        g1 = __builtin_amdgcn_mfma_f32_32x32x16_bf16(a, b1, g1, 0, 0, 0);
    }

    // ---- park next cluster's X rows into E (wave-local rows; DS in-order
    //      guarantees these land after this wave's last E A-reads above) ----
    if (WN) {
        *(short8*)&E[r * XS + cb +  0] = nx0;
        *(short8*)&E[r * XS + cb +  8] = nx1;
        *(short8*)&E[r * XS + cb + 16] = nx2;
        *(short8*)&E[r * XS + cb + 24] = nx3;
    }

    // ---- pack adjacent cols (shfl_xor 1) + pk_add_bf16 scatter ----
    const bool ev = !(lane & 1);
    const int colbase = ev ? m : (31 + m);
    #pragma unroll
    for (int rr = 0; rr < 16; ++rr) {
        int row = w * 32 + crow(rr, lane);
        int nid = ids[row];
        float a0 = g0[rr], a1 = g1[rr];
        float t0 = __shfl_xor(a0, 1, 64);
        float t1 = __shfl_xor(a1, 1, 64);
        float lo = ev ? a0 : t1;
        float hi = ev ? t0 : a1;
        unsigned pk = (unsigned)f2bf(lo) | ((unsigned)f2bf(hi) << 16);
        unsigned long long addr =
            (unsigned long long)(accum_bf + (size_t)nid * 64 + colbase);
        asm volatile("global_atomic_pk_add_bf16 %0, %1, off"
                     :: "v"(addr), "v"(pk) : "memory");
    }
}

__global__ __launch_bounds__(256, 4) void attn_kernel(
    const float* __restrict__ x_var, const float* __restrict__ x_clause,
    const int* __restrict__ cvar, const int* __restrict__ ccl,
    const float* __restrict__ sat, const unsigned short* __restrict__ Mtr,
    unsigned short* __restrict__ accum_bf)
{
    __shared__ unsigned short bufA[128 * XS];  // 18432
    __shared__ unsigned short bufB[128 * XS];  // 18432
    __shared__ int   ids0[128], ids1[128];     // 1024
    __shared__ float bias0[64], bias1[64];     // 512
    // total 38400 B -> 4 blocks/CU

    const int tid = threadIdx.x, lane = tid & 63, w = tid >> 6;
    const int m = lane & 31, hk = (lane >> 5) * 8;
    const int c0 = blockIdx.x * 2;             // this block owns c0, c0+1
    const int r = tid >> 1, half = tid & 1, cb = half * 32;

    // ---- ids for BOTH clusters (issued together -> one latency) ----
    int nid0, nid1;
    const float *src0, *src1;
    float sv0 = 0.f, sv1 = 0.f;
    if (r < 64) {
        nid0 = cvar[c0 * 64 + r];
        nid1 = cvar[c0 * 64 + 64 + r];         // cluster c0+1
        src0 = x_var + (size_t)nid0 * 64;
        src1 = x_var + (size_t)nid1 * 64;
    } else {
        int cid0 = ccl[c0 * 64 + (r - 64)];
        int cid1 = ccl[c0 * 64 + r];           // cluster c0+1
        nid0 = NV + cid0; nid1 = NV + cid1;
        src0 = x_clause + (size_t)cid0 * 64;
        src1 = x_clause + (size_t)cid1 * 64;
        if (half) { sv0 = sat[cid0]; sv1 = sat[cid1]; }
    }

    // ---- issue ALL 16 row loads (both clusters) back-to-back ----
    const float4* s40 = (const float4*)src0 + half * 8;
    const float4* s41 = (const float4*)src1 + half * 8;
    float4 v0[8], v1[8];
    #pragma unroll
    for (int i = 0; i < 8; ++i) v0[i] = s40[i];
    #pragma unroll
    for (int i = 0; i < 8; ++i) v1[i] = s41[i];

    if (!half) { ids0[r] = nid0; ids1[r] = nid1; }   // counts done in prep
    if (r >= 64 && half) { bias0[r - 64] = sv0; bias1[r - 64] = sv1; }

    // ---- c0 -> bufA (row-major bf16) ----
    {
        union { unsigned u[16]; short8 v[4]; } h0;
        #pragma unroll
        for (int i = 0; i < 8; ++i) {
            h0.u[2*i]   = pack2bf(v0[i].x, v0[i].y);
            h0.u[2*i+1] = pack2bf(v0[i].z, v0[i].w);
        }
        #pragma unroll
        for (int i = 0; i < 4; ++i) *(short8*)&bufA[r * XS + cb + i * 8] = h0.v[i];
    }
    // ---- c1 -> 16 packed VGPRs (held across c0 compute) ----
    union { unsigned u[16]; short8 v[4]; } h1;
    #pragma unroll
    for (int i = 0; i < 8; ++i) {
        h1.u[2*i]   = pack2bf(v1[i].x, v1[i].y);
        h1.u[2*i+1] = pack2bf(v1[i].z, v1[i].w);
    }

    bar_lds();   // bufA + ids visible

    // compute c0: X=bufA, scratch=bufB; park c1 rows into bufB near the end
    cluster_compute<true>(bufA, bufB, ids0, bias0, Mtr, accum_bf,
                          lane, w, m, hk, r, cb,
                          h1.v[0], h1.v[1], h1.v[2], h1.v[3]);

    bar_lds();   // all waves done reading bufA/bufB(c0); c1 X now in bufB.
                 // c0's atomic scatter intentionally still in flight.

    // compute c1: X=bufB, scratch=bufA
    short8 zz = {};
    cluster_compute<false>(bufB, bufA, ids1, bias1, Mtr, accum_bf,
                           lane, w, m, hk, r, cb, zz, zz, zz, zz);
}

// finalize (R12-exact): MFMA @ P, then float4 LDS-transpose epilogue.
// T stride 68 f32: row base 272B (16B-aligned), b128 reads at bank floor.
__global__ __launch_bounds__(256, 4) void finalize_kernel(
    const float* __restrict__ x_var, const float* __restrict__ x_clause,
    const unsigned short* __restrict__ accum_bf, const float* __restrict__ countv,
    const unsigned short* __restrict__ Pbf, const float* __restrict__ bout,
    float* __restrict__ out)
{
    __shared__ float T[4][32][68];   // 34816B, one 32x64 tile per wave
    __shared__ float cnts[256];      //  1024B -> total 35840 -> 4 blocks/CU
    const int tid = threadIdx.x, lane = tid & 63, w = tid >> 6;
    const int base = blockIdx.x * 256;
    {
        int n = base + tid;
        cnts[tid] = (n < NN) ? countv[n] : 1.f;
    }
    __syncthreads();

    const int m = lane & 31, hk = (lane >> 5) * 8;
    short8 pb[2][4];                              // P fragments via L1
    #pragma unroll
    for (int nt = 0; nt < 2; ++nt)
        #pragma unroll
        for (int ks = 0; ks < 4; ++ks)
            pb[nt][ks] = *(const short8*)(Pbf + (nt * 32 + m) * 64 + ks * 16 + hk);
    const float bias0 = bout[m], bias1 = bout[32 + m];

    const int r2 = lane >> 1, cb2 = (lane & 1) * 32;   // phase-B mapping

    #pragma unroll
    for (int tm = 0; tm < 2; ++tm) {
        int mt = w * 2 + tm;                      // rows base+mt*32 ..
        const unsigned short* arow = accum_bf + (size_t)(base + mt * 32 + m) * 64;
        floatx16 c0 = {}, c1 = {};
        #pragma unroll
        for (int ks = 0; ks < 4; ++ks) {
            short8 a = *(const short8*)(arow + ks * 16 + hk);
            c0 = __builtin_amdgcn_mfma_f32_32x32x16_bf16(a, pb[0][ks], c0, 0, 0, 0);
            c1 = __builtin_amdgcn_mfma_f32_32x32x16_bf16(a, pb[1][ks], c1, 0, 0, 0);
        }
        // ---- phase A: stage (c*inv + bias) to wave-private T ----
        #pragma unroll
        for (int rr = 0; rr < 16; ++rr) {
            int lr32 = crow(rr, lane);            // 0..31 within tile
            float inv = 1.0f / fmaxf(cnts[mt * 32 + lr32], 1.0f);
            T[w][lr32][m]      = c0[rr] * inv + bias0;
            T[w][lr32][32 + m] = c1[rr] * inv + bias1;
        }
        // wave-local DS is in-order: reads below see this wave's writes.
        // ---- phase B: float4 x-add + out-store (2 rows per lane-pair) ----
        int n2 = base + mt * 32 + r2;
        if (n2 < NN) {
            const float* xr = (n2 < NV) ? (x_var + (size_t)n2 * 64)
                                        : (x_clause + (size_t)(n2 - NV) * 64);
            float* orow = out + (size_t)n2 * 64;
            #pragma unroll
            for (int j = 0; j < 8; ++j) {
                float4 t = *(const float4*)&T[w][r2][cb2 + 4 * j];
                float4 xv = *(const float4*)&xr[cb2 + 4 * j];
                float4 o;
                o.x = t.x + xv.x; o.y = t.y + xv.y;
                o.z = t.z + xv.z; o.w = t.w + xv.w;
                *(float4*)&orow[cb2 + 4 * j] = o;
            }
        }
    }
}

extern "C" void kernel_launch(void* const* d_in, const int* in_sizes, int n_in,
                              void* d_out, int out_size, void* d_ws, size_t ws_size,
                              hipStream_t stream)
{
    const float* x_var        = (const float*)d_in[0];
    const float* x_clause     = (const float*)d_in[1];
    const int*   cvar         = (const int*)d_in[4];
    const int*   ccl          = (const int*)d_in[5];
    const float* sat          = (const float*)d_in[6];
    const int*   active_heads = (const int*)d_in[7];
    const float* WQ           = (const float*)d_in[8];
    const float* WK           = (const float*)d_in[9];
    const float* WV           = (const float*)d_in[10];
    const float* head_weights = (const float*)d_in[11];
    const float* Wout         = (const float*)d_in[12];
    const float* bout         = (const float*)d_in[13];

    unsigned short* accum_bf = (unsigned short*)d_ws;          // NN*64 bf16
    float* countv = (float*)(accum_bf + (size_t)NN * 64);      // NN f32
    unsigned short* Mtr = (unsigned short*)(countv + NN);      // 4096 bf16
    unsigned short* Pbf = Mtr + 4096;                          // 4096 bf16

    // countv zeroed by a small memset; prep zeroes accum (25.6MB) + counts
    hipMemsetAsync(countv, 0, (size_t)NN * 4, stream);
    prep_kernel<<<1024, 256, 0, stream>>>(WQ, WK, WV, Wout, head_weights,
                                          active_heads, cvar, ccl, Mtr, Pbf,
                                          (uint4v*)d_ws, countv);
    attn_kernel<<<NCLUST / 2, 256, 0, stream>>>(
        x_var, x_clause, cvar, ccl, sat, Mtr, accum_bf);
    finalize_kernel<<<(NN + 255) / 256, 256, 0, stream>>>(
        x_var, x_clause, accum_bf, countv, Pbf, bout, (float*)d_out);
}